// Round 17
// baseline (72.671 us; speedup 1.0000x reference)
//
#include <hip/hip_runtime.h>

// B=4, N=384, D=64, K=2 hops
#define BB 4
#define NN 384
#define DD 64
#define ANN (BB*NN*NN)      // 589824 pairs (one per (b,j,l))
#define XND (BB*NN*DD)      // 98304 floats per X time-slice

// ws layout (floats):
//   A0c [0, ANN)                    packed hop-0 adjacency [b][j][l]
//   A1c [ANN, 2*ANN)                packed hop-1 adjacency
//   X0c [2*ANN + 0*XND, ...)        packed X t=0  [b][n][d]
//   X1c [2*ANN + 1*XND, ...)
//   X2c [2*ANN + 2*XND, ...)
//   U   [2*ANN + 3*XND, ...)        intermediate
#define OFF_A0 0
#define OFF_A1 ANN
#define OFF_X0 (2*ANN)
#define OFF_X1 (2*ANN + XND)
#define OFF_X2 (2*ANN + 2*XND)
#define OFF_U  (2*ANN + 3*XND)

#define A_THREADS (ANN/4)            // 147456: each packs 4 (h0,h1) pairs
#define X_THREADS (XND/4)            // 24576:  each packs one d-quad (3 t-planes)
#define G1_BLOCKS ((A_THREADS + X_THREADS) / 256)   // 672

// g1: single streaming pass over A and X, fully coalesced float4 reads,
// writes packed planes into ws (lines stay hot in L2/L3 for g2/g3).
__global__ __launch_bounds__(256) void g1_pack(const float* __restrict__ A,
                                               const float* __restrict__ X,
                                               float* __restrict__ ws) {
    const int gid = blockIdx.x * 256 + threadIdx.x;
    if (gid < A_THREADS) {
        const float4* A4 = (const float4*)A;
        float4 fa = A4[gid * 2];        // pairs p0,p1: {h0,h1,h0,h1}
        float4 fb = A4[gid * 2 + 1];    // pairs p2,p3
        float4 a0 = {fa.x, fa.z, fb.x, fb.z};
        float4 a1 = {fa.y, fa.w, fb.y, fb.w};
        *(float4*)&ws[OFF_A0 + gid * 4] = a0;
        *(float4*)&ws[OFF_A1 + gid * 4] = a1;
    } else {
        const int u   = gid - A_THREADS;       // 0..24575
        const int row = u >> 4, dq = u & 15;   // row = b*NN+n ; dq = d quad
        const float* src = X + (size_t)row * (DD * 3) + dq * 12;
        float4 s0 = *(const float4*)(src + 0);
        float4 s1 = *(const float4*)(src + 4);
        float4 s2 = *(const float4*)(src + 8);
        float4 x0 = {s0.x, s0.w, s1.z, s2.y};
        float4 x1 = {s0.y, s1.x, s1.w, s2.z};
        float4 x2 = {s0.z, s1.y, s2.x, s2.w};
        const size_t dst = (size_t)row * DD + dq * 4;
        *(float4*)&ws[OFF_X0 + dst] = x0;
        *(float4*)&ws[OFF_X1 + dst] = x1;
        *(float4*)&ws[OFF_X2 + dst] = x2;
    }
}

#define FMA4(c, a, x)                          \
    c.x = fmaf(a, x.x, c.x);                   \
    c.y = fmaf(a, x.y, c.y);                   \
    c.z = fmaf(a, x.z, c.z);                   \
    c.w = fmaf(a, x.w, c.w);

#define RED4(c)                                                         \
    c.x += __shfl_xor(c.x, 16); c.y += __shfl_xor(c.y, 16);             \
    c.z += __shfl_xor(c.z, 16); c.w += __shfl_xor(c.w, 16);             \
    c.x += __shfl_xor(c.x, 32); c.y += __shfl_xor(c.y, 32);             \
    c.z += __shfl_xor(c.z, 32); c.w += __shfl_xor(c.w, 32);

// g2: U[b,j,:] = X1c[b,j,:] + sum_l A1c[b,j,l] * X2c[b,l,:]
// 2 rows/block, 768 blocks; wave ks = K-quarter; lane = (jsub = l mod 4, dg)
__global__ __launch_bounds__(256) void g2_u(const float* __restrict__ ws_c,
                                            float* __restrict__ ws) {
    __shared__ float part[4][2][DD];
    const float* A1c = ws_c + OFF_A1;
    const float* X1c = ws_c + OFF_X1;
    const float* X2c = ws_c + OFF_X2;
    float* U = ws + OFF_U;

    const int tid = threadIdx.x, lane = tid & 63, ks = tid >> 6;
    const int dg = lane & 15, jsub = lane >> 4;
    const int lbid = ((int)blockIdx.x & 7) * 96 + ((int)blockIdx.x >> 3); // 768%8==0
    const int b = lbid / 192, j0 = (lbid % 192) * 2;

    const int lb = ks * 96 + jsub;
    const float* xp = X2c + ((size_t)b * NN + lb) * DD + dg * 4;
    const float* a0 = A1c + ((size_t)b * NN + j0 + 0) * NN + lb;  // packed, stride-1 in l
    const float* a1 = A1c + ((size_t)b * NN + j0 + 1) * NN + lb;

    float4 c0{0,0,0,0}, c1{0,0,0,0};
    #pragma unroll 8
    for (int s = 0; s < 24; ++s) {              // l = lb + s*4
        float4 x = *(const float4*)(xp + s * 4 * DD);
        float v0 = a0[s * 4], v1 = a1[s * 4];
        FMA4(c0, v0, x) FMA4(c1, v1, x)
    }
    RED4(c0) RED4(c1)
    if (jsub == 0) {
        *(float4*)&part[ks][0][dg * 4] = c0;
        *(float4*)&part[ks][1][dg * 4] = c1;
    }
    __syncthreads();

    const int w = ks;
    if (w < 2) {
        float t = X1c[((size_t)b * NN + j0 + w) * DD + lane];
        t += part[0][w][lane] + part[1][w][lane] + part[2][w][lane] + part[3][w][lane];
        U[((size_t)b * NN + j0 + w) * DD + lane] = t;
    }
}

// g3: out[b,i,:] = (X0c[b,i,:] + sum_j A0c[b,i,j] * U[b,j,:]) @ W
__global__ __launch_bounds__(256) void g3_out(const float* __restrict__ W,
                                              const float* __restrict__ ws_c,
                                              float* __restrict__ out) {
    __shared__ float part[4][2][DD];
    __shared__ float Ts[2][DD];
    __shared__ float Wsm[DD * DD];
    const float* A0c = ws_c + OFF_A0;
    const float* X0c = ws_c + OFF_X0;
    const float* U   = ws_c + OFF_U;

    const int tid = threadIdx.x, lane = tid & 63, ks = tid >> 6;
    const int dg = lane & 15, jsub = lane >> 4;
    const int lbid = ((int)blockIdx.x & 7) * 96 + ((int)blockIdx.x >> 3);
    const int b = lbid / 192, i0 = (lbid % 192) * 2;

    // stage W (coalesced float4), visible after first barrier
    #pragma unroll
    for (int it = 0; it < 4; ++it) {
        int i4 = it * 256 + tid;
        *(float4*)&Wsm[i4 * 4] = ((const float4*)W)[i4];
    }

    const int lb = ks * 96 + jsub;
    const float* xp = U + ((size_t)b * NN + lb) * DD + dg * 4;
    const float* a0 = A0c + ((size_t)b * NN + i0 + 0) * NN + lb;
    const float* a1 = A0c + ((size_t)b * NN + i0 + 1) * NN + lb;

    float4 c0{0,0,0,0}, c1{0,0,0,0};
    #pragma unroll 8
    for (int s = 0; s < 24; ++s) {
        float4 x = *(const float4*)(xp + s * 4 * DD);
        float v0 = a0[s * 4], v1 = a1[s * 4];
        FMA4(c0, v0, x) FMA4(c1, v1, x)
    }
    RED4(c0) RED4(c1)
    if (jsub == 0) {
        *(float4*)&part[ks][0][dg * 4] = c0;
        *(float4*)&part[ks][1][dg * 4] = c1;
    }
    __syncthreads();

    const int w = ks;
    if (w < 2) {
        float t = X0c[((size_t)b * NN + i0 + w) * DD + lane];
        t += part[0][w][lane] + part[1][w][lane] + part[2][w][lane] + part[3][w][lane];
        Ts[w][lane] = t;
    }
    __syncthreads();

    if (w < 2) {
        float o = 0.f;
        #pragma unroll 16
        for (int d = 0; d < DD; ++d)
            o = fmaf(Ts[w][d], Wsm[d * DD + lane], o);   // broadcast * stride-1
        out[((size_t)b * NN + i0 + w) * DD + lane] = o;
    }
}

extern "C" void kernel_launch(void* const* d_in, const int* in_sizes, int n_in,
                              void* d_out, int out_size, void* d_ws, size_t ws_size,
                              hipStream_t stream) {
    const float* A = (const float*)d_in[0];
    const float* X = (const float*)d_in[1];
    const float* W = (const float*)d_in[2];
    float* out = (float*)d_out;
    float* ws  = (float*)d_ws;   // uses (2*ANN + 4*XND)*4 ≈ 6.3 MB

    g1_pack<<<dim3(G1_BLOCKS),   dim3(256), 0, stream>>>(A, X, ws);   // 672 blocks
    g2_u   <<<dim3(BB * NN / 2), dim3(256), 0, stream>>>(ws, ws);     // 768 blocks
    g3_out <<<dim3(BB * NN / 2), dim3(256), 0, stream>>>(W, ws, out); // 768 blocks
}